// Round 9
// baseline (528.984 us; speedup 1.0000x reference)
//
#include <hip/hip_runtime.h>

#define HDIM 128
#define XDIM 66
#define EDIM 6
#define NGRAPHS 256
#define LN_EPS 1e-5f

#define HBINS 25600          // bins per range (100 KB LDS)
#define HR 4                 // ranges: HR*HBINS = 102400 >= N
#define HB 16                // edge slices per (range, array)
#define CBINS (HR * HBINS)
#define NBX 1024             // k_xsum grid
#define KP 104               // padded K for bf16 MFMA

typedef __attribute__((ext_vector_type(8))) short sv8;
typedef __attribute__((ext_vector_type(4))) float fv4;

__device__ __forceinline__ unsigned short f2bf(float f) {
    unsigned u = __float_as_uint(f);
    return (unsigned short)((u + 0x7FFFu + ((u >> 16) & 1u)) >> 16);
}
__device__ __forceinline__ float bf2f(unsigned short u) {
    return __uint_as_float((unsigned)u << 16);
}

// ---------------- K1: hist partials + edge_attr colsum + W^T prep (merged) ----------------
// blocks 0..127: histogram; 128..191: edgesum; 192: bf16 W^T prep
__global__ __launch_bounds__(256) void k_pre(const int* __restrict__ ei,
        float* __restrict__ part, int E, const float* __restrict__ ea,
        float* __restrict__ sum_attr, const float* __restrict__ w_node,
        unsigned short* __restrict__ wtg) {
    __shared__ float lh[HBINS];
    int b = blockIdx.x;
    int t = threadIdx.x;
    if (b < 2 * HR * HB) {
        int s = b & (HB - 1);
        int r = (b / HB) & (HR - 1);
        int a = b / (HB * HR);
        for (int i = t; i < HBINS; i += 256) lh[i] = 0.f;
        __syncthreads();
        const int* src = ei + (size_t)a * E;
        int chunk = (((E + HB - 1) / HB) + 3) & ~3;
        int lo = s * chunk;
        int hi = min(E, lo + chunk);
        int base = r * HBINS;
        if ((E & 3) == 0) {
            for (int i = lo + t * 4; i < hi; i += 256 * 4) {
                if (i + 4 <= hi) {
                    int4 v = *(const int4*)(src + i);
                    unsigned u0 = (unsigned)(v.x - base);
                    unsigned u1 = (unsigned)(v.y - base);
                    unsigned u2 = (unsigned)(v.z - base);
                    unsigned u3 = (unsigned)(v.w - base);
                    if (u0 < HBINS) atomicAdd(&lh[u0], 1.0f);
                    if (u1 < HBINS) atomicAdd(&lh[u1], 1.0f);
                    if (u2 < HBINS) atomicAdd(&lh[u2], 1.0f);
                    if (u3 < HBINS) atomicAdd(&lh[u3], 1.0f);
                } else {
                    for (int j = i; j < hi; ++j) {
                        unsigned u = (unsigned)(src[j] - base);
                        if (u < HBINS) atomicAdd(&lh[u], 1.0f);
                    }
                }
            }
        } else {
            for (int i = lo + t; i < hi; i += 256) {
                unsigned u = (unsigned)(src[i] - base);
                if (u < HBINS) atomicAdd(&lh[u], 1.0f);
            }
        }
        __syncthreads();
        float* dst = part + (size_t)b * HBINS;
        for (int i = t; i < HBINS / 4; i += 256)
            ((float4*)dst)[i] = ((const float4*)lh)[i];
    } else if (b < 2 * HR * HB + 64) {
        int b2 = b - 2 * HR * HB;
        int nchunk = E >> 1;
        float a0 = 0, a1 = 0, a2 = 0, a3 = 0, a4 = 0, a5 = 0;
        for (int c = b2 * 256 + t; c < nchunk; c += 64 * 256) {
            const float4* p = (const float4*)(ea + (size_t)c * 12);
            float4 v0 = p[0], v1 = p[1], v2 = p[2];
            a0 += v0.x + v1.z;  a1 += v0.y + v1.w;  a2 += v0.z + v2.x;
            a3 += v0.w + v2.y;  a4 += v1.x + v2.z;  a5 += v1.y + v2.w;
        }
#pragma unroll
        for (int m = 32; m; m >>= 1) {
            a0 += __shfl_xor(a0, m); a1 += __shfl_xor(a1, m); a2 += __shfl_xor(a2, m);
            a3 += __shfl_xor(a3, m); a4 += __shfl_xor(a4, m); a5 += __shfl_xor(a5, m);
        }
        float (*sb)[6] = (float(*)[6])lh;
        int lane = t & 63, w = t >> 6;
        if (lane == 0) {
            sb[w][0] = a0; sb[w][1] = a1; sb[w][2] = a2;
            sb[w][3] = a3; sb[w][4] = a4; sb[w][5] = a5;
        }
        __syncthreads();
        if (t < 6) {
            float s = sb[0][t] + sb[1][t] + sb[2][t] + sb[3][t];
            atomicAdd(&sum_attr[t], s);
        }
        if (b2 == 0 && t < 6 && (E & 1))
            atomicAdd(&sum_attr[t], ea[(size_t)(E - 1) * 6 + t]);
    } else {
        if (t < 128) {
            for (int kp = 0; kp < KP; ++kp) {
                float v = (kp < XDIM) ? w_node[kp * HDIM + t] : 0.f;
                wtg[t * KP + kp] = f2bf(v);
            }
        }
    }
}

// ---------------- K1b: reduce slices -> c_src, c_dst ----------------
__global__ __launch_bounds__(256) void k_hist_red(const float* __restrict__ part,
        float* __restrict__ c_src, float* __restrict__ c_dst) {
    int n = blockIdx.x * 256 + threadIdx.x;
    if (n >= CBINS) return;
    int r = n / HBINS, off = n - r * HBINS;
    const float* p0 = part + ((size_t)(0 * HR + r) * HB) * HBINS + off;
    const float* p1 = part + ((size_t)(1 * HR + r) * HB) * HBINS + off;
    float s0 = 0.f, s1 = 0.f;
#pragma unroll 8
    for (int s = 0; s < HB; ++s) {
        s0 += p0[(size_t)s * HBINS];
        s1 += p1[(size_t)s * HBINS];
    }
    c_src[n] = s0;
    c_dst[n] = s1;
}

// ---------------- K3: weighted column sums of x -> per-block partials ----------------
__global__ __launch_bounds__(256) void k_xsum(const float* __restrict__ x,
        const float* __restrict__ c_src, const float* __restrict__ c_dst,
        float* __restrict__ xpart, int N) {
    int lane = threadIdx.x & 63, w = threadIdx.x >> 6;
    int wid = blockIdx.x * 4 + w, nw = gridDim.x * 4;
    float as0 = 0, ad0 = 0, as1 = 0, ad1 = 0;
    int Q = N >> 2;
    for (int q = wid; q < Q; q += nw) {
        int n = q * 4;
        const float* xr = x + (size_t)n * XDIM;
        float x0 = xr[lane];
        float x1 = xr[XDIM + lane];
        float x2 = xr[2 * XDIM + lane];
        float x3 = xr[3 * XDIM + lane];
        float4 cs = *(const float4*)(c_src + n);
        float4 cd = *(const float4*)(c_dst + n);
        as0 = fmaf(cs.x, x0, as0); as0 = fmaf(cs.y, x1, as0);
        as0 = fmaf(cs.z, x2, as0); as0 = fmaf(cs.w, x3, as0);
        ad0 = fmaf(cd.x, x0, ad0); ad0 = fmaf(cd.y, x1, ad0);
        ad0 = fmaf(cd.z, x2, ad0); ad0 = fmaf(cd.w, x3, ad0);
        if (lane < 2) {
            float e0 = xr[64 + lane];
            float e1 = xr[XDIM + 64 + lane];
            float e2 = xr[2 * XDIM + 64 + lane];
            float e3 = xr[3 * XDIM + 64 + lane];
            as1 = fmaf(cs.x, e0, as1); as1 = fmaf(cs.y, e1, as1);
            as1 = fmaf(cs.z, e2, as1); as1 = fmaf(cs.w, e3, as1);
            ad1 = fmaf(cd.x, e0, ad1); ad1 = fmaf(cd.y, e1, ad1);
            ad1 = fmaf(cd.z, e3, ad1); ad1 = fmaf(cd.w, e3, ad1);
        }
    }
    if (wid == 0) {
        for (int n = Q * 4; n < N; ++n) {
            const float* xr = x + (size_t)n * XDIM;
            float cs = c_src[n], cd = c_dst[n];
            float xv = xr[lane];
            as0 = fmaf(cs, xv, as0);
            ad0 = fmaf(cd, xv, ad0);
            if (lane < 2) {
                float xe = xr[64 + lane];
                as1 = fmaf(cs, xe, as1);
                ad1 = fmaf(cd, xe, ad1);
            }
        }
    }
    __shared__ float redS[4][XDIM], redD[4][XDIM];
    redS[w][lane] = as0;  redD[w][lane] = ad0;
    if (lane < 2) { redS[w][64 + lane] = as1;  redD[w][64 + lane] = ad1; }
    __syncthreads();
    int t = threadIdx.x;
    float* xp = xpart + (size_t)blockIdx.x * 136;
    if (t < XDIM) {
        xp[t]        = redS[0][t] + redS[1][t] + redS[2][t] + redS[3][t];
        xp[XDIM + t] = redD[0][t] + redD[1][t] + redD[2][t] + redD[3][t];
    }
}

// ---------------- K6: mean_msg; folds the partial reduction ----------------
// FIRST=1: src = xpart (nb x 136); FIRST=0: src = partials (nb x 512)
template <int FIRST>
__global__ __launch_bounds__(256) void k_mm(const float* __restrict__ src, int nb,
        const float* __restrict__ sum_attr, const float* __restrict__ w_edge,
        const float* __restrict__ b_edge, const float* __restrict__ W,
        const float* __restrict__ mpb, float* __restrict__ mean_msg, float Ef,
        const float* __restrict__ w_node, const float* __restrict__ b_node) {
    __shared__ float svl[512];
    __shared__ float sc[384];
    __shared__ float mred[256];
    int t = threadIdx.x;
    if (FIRST) {
        if (t < 136) {
            float a0 = 0, a1 = 0, a2 = 0, a3 = 0;
            int b = 0;
            for (; b + 4 <= nb; b += 4) {
                a0 += src[(size_t)b * 136 + t];
                a1 += src[(size_t)(b + 1) * 136 + t];
                a2 += src[(size_t)(b + 2) * 136 + t];
                a3 += src[(size_t)(b + 3) * 136 + t];
            }
            for (; b < nb; ++b) a0 += src[(size_t)b * 136 + t];
            svl[t] = a0 + a1 + a2 + a3;
        }
    } else {
        float a0 = 0, a1 = 0, b0 = 0, b1 = 0;
        int b = 0;
        for (; b + 2 <= nb; b += 2) {
            a0 += src[(size_t)b * 512 + t];
            b0 += src[(size_t)b * 512 + 256 + t];
            a1 += src[(size_t)(b + 1) * 512 + t];
            b1 += src[(size_t)(b + 1) * 512 + 256 + t];
        }
        for (; b < nb; ++b) {
            a0 += src[(size_t)b * 512 + t];
            b0 += src[(size_t)b * 512 + 256 + t];
        }
        svl[t] = a0 + a1;
        svl[256 + t] = b0 + b1;
    }
    __syncthreads();
    if (t < 128) {
        float ssrc, sdst;
        if (FIRST) {
            ssrc = Ef * b_node[t];
            sdst = ssrc;
#pragma unroll
            for (int k = 0; k < XDIM; ++k) {
                float wv = w_node[k * HDIM + t];
                ssrc = fmaf(svl[k], wv, ssrc);
                sdst = fmaf(svl[XDIM + k], wv, sdst);
            }
        } else {
            ssrc = svl[t] + svl[t + 128];
            sdst = svl[256 + t] + svl[384 + t];
        }
        sc[t] = ssrc;
        sc[128 + t] = sdst;
        float se = Ef * b_edge[t];
#pragma unroll
        for (int k = 0; k < EDIM; ++k) se = fmaf(sum_attr[k], w_edge[k * HDIM + t], se);
        sc[256 + t] = se;
    }
    __syncthreads();
    int col = blockIdx.x * 16 + (t & 15);
    int rg = t >> 4;
    float acc = 0.f;
#pragma unroll 4
    for (int r = rg * 24; r < rg * 24 + 24; ++r)
        acc = fmaf(sc[r], W[r * HDIM + col], acc);
    mred[t] = acc;
    __syncthreads();
    if (t < 16) {
        float s = 0.f;
#pragma unroll
        for (int g = 0; g < 16; ++g) s += mred[g * 16 + t];
        mean_msg[blockIdx.x * 16 + t] = s / Ef + mpb[blockIdx.x * 16 + t];
    }
}

// ---------------- K7: fused layer-0 via bf16 MFMA; h stored bf16 ----------------
__global__ __launch_bounds__(256) void k_upd0(
        const float* __restrict__ x, const unsigned short* __restrict__ wtg,
        const float* __restrict__ b_node, const float* __restrict__ mean_msg,
        const float* __restrict__ ln_g, const float* __restrict__ ln_b,
        const float* __restrict__ c_src, const float* __restrict__ c_dst,
        unsigned short* __restrict__ h, float* __restrict__ partials, int N) {
    __shared__ unsigned short xl[64 * KP];
    __shared__ unsigned short wt[128 * KP];
    int t = threadIdx.x;
    int lane = t & 63, w = t >> 6;
    {
        const uint4* srcp = (const uint4*)wtg;
        uint4* dstp = (uint4*)wt;
        for (int i = t; i < 128 * KP / 8; i += 256) dstp[i] = srcp[i];
    }
    for (int i = t; i < 64 * KP / 2; i += 256) ((unsigned*)xl)[i] = 0u;
    __syncthreads();
    int rowbase = blockIdx.x * 64;
    const float* xg = x + (size_t)rowbase * XDIM;
    int lim = min(64, N - rowbase) * XDIM;
    for (int i = t; i < 64 * XDIM; i += 256) {
        if (i < lim) {
            int r = i / XDIM, k = i - r * XDIM;
            xl[r * KP + k] = f2bf(xg[i]);
        }
    }
    int cl = lane & 15, g = lane >> 4;
    float bm[8], gg[8], lb[8];
#pragma unroll
    for (int ct = 0; ct < 8; ++ct) {
        int col = ct * 16 + cl;
        bm[ct] = b_node[col] + mean_msg[col];
        gg[ct] = ln_g[col];
        lb[ct] = ln_b[col];
    }
    __syncthreads();

    fv4 acc[8];
#pragma unroll
    for (int ct = 0; ct < 8; ++ct) acc[ct] = (fv4){0.f, 0.f, 0.f, 0.f};
#pragma unroll
    for (int ks = 0; ks < 3; ++ks) {
        sv8 a = *(const sv8*)&xl[(w * 16 + cl) * KP + ks * 32 + g * 8];
#pragma unroll
        for (int ct = 0; ct < 8; ++ct) {
            sv8 b = *(const sv8*)&wt[(ct * 16 + cl) * KP + ks * 32 + g * 8];
            acc[ct] = __builtin_amdgcn_mfma_f32_16x16x32_bf16(a, b, acc[ct], 0, 0, 0);
        }
    }
    float v[8][4];
    float s[4] = {0.f, 0.f, 0.f, 0.f};
#pragma unroll
    for (int ct = 0; ct < 8; ++ct)
#pragma unroll
        for (int e = 0; e < 4; ++e) {
            v[ct][e] = acc[ct][e] + bm[ct];
            s[e] += v[ct][e];
        }
#pragma unroll
    for (int m = 1; m < 16; m <<= 1) {
        s[0] += __shfl_xor(s[0], m); s[1] += __shfl_xor(s[1], m);
        s[2] += __shfl_xor(s[2], m); s[3] += __shfl_xor(s[3], m);
    }
    float mu[4], q[4] = {0.f, 0.f, 0.f, 0.f};
#pragma unroll
    for (int e = 0; e < 4; ++e) mu[e] = s[e] * (1.0f / HDIM);
#pragma unroll
    for (int ct = 0; ct < 8; ++ct)
#pragma unroll
        for (int e = 0; e < 4; ++e) {
            float d = v[ct][e] - mu[e];
            q[e] = fmaf(d, d, q[e]);
        }
#pragma unroll
    for (int m = 1; m < 16; m <<= 1) {
        q[0] += __shfl_xor(q[0], m); q[1] += __shfl_xor(q[1], m);
        q[2] += __shfl_xor(q[2], m); q[3] += __shfl_xor(q[3], m);
    }
    float rs[4];
#pragma unroll
    for (int e = 0; e < 4; ++e) rs[e] = rsqrtf(q[e] * (1.0f / HDIM) + LN_EPS);

    int grow = rowbase + w * 16 + g * 4;
    float4 csv = *(const float4*)(c_src + grow);
    float4 cdv = *(const float4*)(c_dst + grow);
    float cs[4] = {csv.x, csv.y, csv.z, csv.w};
    float cd[4] = {cdv.x, cdv.y, cdv.z, cdv.w};
    float accS[8], accD[8];
#pragma unroll
    for (int ct = 0; ct < 8; ++ct) { accS[ct] = 0.f; accD[ct] = 0.f; }
#pragma unroll
    for (int e = 0; e < 4; ++e) {
        int row = grow + e;
        bool ok = (row < N);
#pragma unroll
        for (int ct = 0; ct < 8; ++ct) {
            float o = fmaxf(0.f, fmaf((v[ct][e] - mu[e]) * rs[e], gg[ct], lb[ct]));
            if (ok) h[(size_t)row * HDIM + ct * 16 + cl] = f2bf(o);
            accS[ct] = fmaf(cs[e], o, accS[ct]);
            accD[ct] = fmaf(cd[e], o, accD[ct]);
        }
    }
#pragma unroll
    for (int ct = 0; ct < 8; ++ct) {
        accS[ct] += __shfl_xor(accS[ct], 16); accS[ct] += __shfl_xor(accS[ct], 32);
        accD[ct] += __shfl_xor(accD[ct], 16); accD[ct] += __shfl_xor(accD[ct], 32);
    }
    __syncthreads();
    float* redS = (float*)xl;
    float* redD = redS + 512;
    if (g == 0) {
#pragma unroll
        for (int ct = 0; ct < 8; ++ct) {
            redS[w * HDIM + ct * 16 + cl] = accS[ct];
            redD[w * HDIM + ct * 16 + cl] = accD[ct];
        }
    }
    __syncthreads();
    if (t < 128) {
        float ss = redS[t] + redS[128 + t] + redS[256 + t] + redS[384 + t];
        float dd = redD[t] + redD[128 + t] + redD[256 + t] + redD[384 + t];
        float* row = partials + (size_t)blockIdx.x * 512;
        row[t] = ss;       row[t + 128] = 0.f;
        row[t + 256] = dd; row[t + 384] = 0.f;
    }
}

// ---------------- LN helper: 32-lane group, 4 cols/lane ----------------
__device__ __forceinline__ float4 ln_row4(const unsigned short* hp,
        float4 mm, float4 g, float4 bb) {
    ushort4 hv = *(const ushort4*)hp;
    float4 v;
    v.x = bf2f(hv.x) + mm.x; v.y = bf2f(hv.y) + mm.y;
    v.z = bf2f(hv.z) + mm.z; v.w = bf2f(hv.w) + mm.w;
    float s = v.x + v.y + v.z + v.w;
#pragma unroll
    for (int m = 1; m < 32; m <<= 1) s += __shfl_xor(s, m);
    float mu = s * (1.0f / HDIM);
    float d0 = v.x - mu, d1 = v.y - mu, d2 = v.z - mu, d3 = v.w - mu;
    float q = d0 * d0 + d1 * d1 + d2 * d2 + d3 * d3;
#pragma unroll
    for (int m = 1; m < 32; m <<= 1) q += __shfl_xor(q, m);
    float rs = rsqrtf(q * (1.0f / HDIM) + LN_EPS);
    float4 o;
    o.x = fmaxf(0.f, fmaf(d0 * rs, g.x, bb.x));
    o.y = fmaxf(0.f, fmaf(d1 * rs, g.y, bb.y));
    o.z = fmaxf(0.f, fmaf(d2 * rs, g.z, bb.z));
    o.w = fmaxf(0.f, fmaf(d3 * rs, g.w, bb.w));
    return o;
}

// ---------------- K8: h = relu(LN(h + mm)) bf16; next-layer sums or pooling ----------------
template <int LAST>
__global__ __launch_bounds__(256) void k_update(
        unsigned short* __restrict__ h, const float* __restrict__ mean_msg,
        const float* __restrict__ ln_g, const float* __restrict__ ln_b,
        const float* __restrict__ c_src, const float* __restrict__ c_dst,
        const int* __restrict__ batch, float* __restrict__ partials,
        float* __restrict__ pooled, int N, int cpb) {
    int t = threadIdx.x;
    int lane = t & 63, w = t >> 6;
    int half = lane >> 5, cl = lane & 31;
    int c0 = cl * 4;
    float4 mm = *(const float4*)(mean_msg + c0);
    float4 g  = *(const float4*)(ln_g + c0);
    float4 bb = *(const float4*)(ln_b + c0);
    int start = blockIdx.x * cpb;
    int end = min(N, start + cpb);
    int spw = (cpb + 3) >> 2;
    int ns = start + w * spw;
    int ne = min(end, ns + spw);
    float4 accS = {0,0,0,0}, accD = {0,0,0,0}, accP = {0,0,0,0};
    int cur_g = -1;
    int n = ns;
    for (; n + 4 <= ne; n += 4) {
        int rA = n + half, rB = n + 2 + half;
        float4 oA = ln_row4(h + (size_t)rA * HDIM + c0, mm, g, bb);
        float4 oB = ln_row4(h + (size_t)rB * HDIM + c0, mm, g, bb);
        if (LAST) {
            int gA = batch[rA], gB = batch[rB];
            if (gA != cur_g) {
                if (cur_g >= 0) {
                    atomicAdd(&pooled[cur_g * HDIM + c0],     accP.x);
                    atomicAdd(&pooled[cur_g * HDIM + c0 + 1], accP.y);
                    atomicAdd(&pooled[cur_g * HDIM + c0 + 2], accP.z);
                    atomicAdd(&pooled[cur_g * HDIM + c0 + 3], accP.w);
                }
                accP = (float4){0,0,0,0};
                cur_g = gA;
            }
            accP.x += oA.x; accP.y += oA.y; accP.z += oA.z; accP.w += oA.w;
            if (gB != cur_g) {
                if (cur_g >= 0) {
                    atomicAdd(&pooled[cur_g * HDIM + c0],     accP.x);
                    atomicAdd(&pooled[cur_g * HDIM + c0 + 1], accP.y);
                    atomicAdd(&pooled[cur_g * HDIM + c0 + 2], accP.z);
                    atomicAdd(&pooled[cur_g * HDIM + c0 + 3], accP.w);
                }
                accP = (float4){0,0,0,0};
                cur_g = gB;
            }
            accP.x += oB.x; accP.y += oB.y; accP.z += oB.z; accP.w += oB.w;
        } else {
            ushort4 pA = {f2bf(oA.x), f2bf(oA.y), f2bf(oA.z), f2bf(oA.w)};
            ushort4 pB = {f2bf(oB.x), f2bf(oB.y), f2bf(oB.z), f2bf(oB.w)};
            *(ushort4*)(h + (size_t)rA * HDIM + c0) = pA;
            *(ushort4*)(h + (size_t)rB * HDIM + c0) = pB;
            float csA = c_src[rA], cdA = c_dst[rA];
            float csB = c_src[rB], cdB = c_dst[rB];
            accS.x = fmaf(csA, oA.x, accS.x); accS.y = fmaf(csA, oA.y, accS.y);
            accS.z = fmaf(csA, oA.z, accS.z); accS.w = fmaf(csA, oA.w, accS.w);
            accS.x = fmaf(csB, oB.x, accS.x); accS.y = fmaf(csB, oB.y, accS.y);
            accS.z = fmaf(csB, oB.z, accS.z); accS.w = fmaf(csB, oB.w, accS.w);
            accD.x = fmaf(cdA, oA.x, accD.x); accD.y = fmaf(cdA, oA.y, accD.y);
            accD.z = fmaf(cdA, oA.z, accD.z); accD.w = fmaf(cdA, oA.w, accD.w);
            accD.x = fmaf(cdB, oB.x, accD.x); accD.y = fmaf(cdB, oB.y, accD.y);
            accD.z = fmaf(cdB, oB.z, accD.z); accD.w = fmaf(cdB, oB.w, accD.w);
        }
    }
    for (; n < ne; n += 2) {
        int row = n + half;
        bool ok = row < ne;
        int rsafe = ok ? row : (N - 1);
        float4 o = ln_row4(h + (size_t)rsafe * HDIM + c0, mm, g, bb);
        if (LAST) {
            if (ok) {
                int gg2 = batch[row];
                if (gg2 != cur_g) {
                    if (cur_g >= 0) {
                        atomicAdd(&pooled[cur_g * HDIM + c0],     accP.x);
                        atomicAdd(&pooled[cur_g * HDIM + c0 + 1], accP.y);
                        atomicAdd(&pooled[cur_g * HDIM + c0 + 2], accP.z);
                        atomicAdd(&pooled[cur_g * HDIM + c0 + 3], accP.w);
                    }
                    accP = (float4){0,0,0,0};
                    cur_g = gg2;
                }
                accP.x += o.x; accP.y += o.y; accP.z += o.z; accP.w += o.w;
            }
        } else if (ok) {
            ushort4 pk = {f2bf(o.x), f2bf(o.y), f2bf(o.z), f2bf(o.w)};
            *(ushort4*)(h + (size_t)row * HDIM + c0) = pk;
            float cs = c_src[row], cd = c_dst[row];
            accS.x = fmaf(cs, o.x, accS.x); accS.y = fmaf(cs, o.y, accS.y);
            accS.z = fmaf(cs, o.z, accS.z); accS.w = fmaf(cs, o.w, accS.w);
            accD.x = fmaf(cd, o.x, accD.x); accD.y = fmaf(cd, o.y, accD.y);
            accD.z = fmaf(cd, o.z, accD.z); accD.w = fmaf(cd, o.w, accD.w);
        }
    }
    if (LAST) {
        if (cur_g >= 0) {
            atomicAdd(&pooled[cur_g * HDIM + c0],     accP.x);
            atomicAdd(&pooled[cur_g * HDIM + c0 + 1], accP.y);
            atomicAdd(&pooled[cur_g * HDIM + c0 + 2], accP.z);
            atomicAdd(&pooled[cur_g * HDIM + c0 + 3], accP.w);
        }
    } else {
        __shared__ float redS[8][HDIM], redD[8][HDIM];
        int set = (w << 1) | half;
        *(float4*)(&redS[set][c0]) = accS;
        *(float4*)(&redD[set][c0]) = accD;
        __syncthreads();
        if (t < 128) {
            float ss = 0.f, dd = 0.f;
#pragma unroll
            for (int gi = 0; gi < 8; ++gi) {
                ss += redS[gi][t];
                dd += redD[gi][t];
            }
            float* row = partials + (size_t)blockIdx.x * 512;
            row[t] = ss;       row[t + 128] = 0.f;
            row[t + 256] = dd; row[t + 384] = 0.f;
        }
    }
}

// ---------------- K9: out = (pooled / max(cnt,1)) @ w_out + b_out ----------------
__global__ __launch_bounds__(128) void k_out(const float* __restrict__ pooled,
        const int* __restrict__ batch, const float* __restrict__ w_out,
        const float* __restrict__ b_out, float* __restrict__ out, int N) {
    int gph = blockIdx.x;
    int t = threadIdx.x;
    __shared__ float p[HDIM];
    __shared__ int cntS;
    if (t == 0) {
        int lo = 0, hi = N;
        while (lo < hi) { int mid = (lo + hi) >> 1; if (batch[mid] < gph) lo = mid + 1; else hi = mid; }
        int lo2 = lo, hi2 = N;
        while (lo2 < hi2) { int mid = (lo2 + hi2) >> 1; if (batch[mid] <= gph) lo2 = mid + 1; else hi2 = mid; }
        cntS = lo2 - lo;
    }
    __syncthreads();
    float inv = 1.0f / fmaxf((float)cntS, 1.0f);
    p[t] = pooled[gph * HDIM + t] * inv;
    __syncthreads();
    float acc = b_out[t];
#pragma unroll 8
    for (int k = 0; k < HDIM; ++k) acc = fmaf(p[k], w_out[k * HDIM + t], acc);
    out[gph * HDIM + t] = acc;
}

extern "C" void kernel_launch(void* const* d_in, const int* in_sizes, int n_in,
                              void* d_out, int out_size, void* d_ws, size_t ws_size,
                              hipStream_t stream) {
    const float* x      = (const float*)d_in[0];
    const int*   ei     = (const int*)d_in[1];
    const float* ea     = (const float*)d_in[2];
    const int*   batch  = (const int*)d_in[3];
    const float* w_node = (const float*)d_in[4];
    const float* b_node = (const float*)d_in[5];
    const float* w_edge = (const float*)d_in[6];
    const float* b_edge = (const float*)d_in[7];
    const float* mp_w   = (const float*)d_in[8];
    const float* mp_b   = (const float*)d_in[9];
    const float* ln_g   = (const float*)d_in[10];
    const float* ln_b   = (const float*)d_in[11];
    const float* w_out  = (const float*)d_in[12];
    const float* b_out  = (const float*)d_in[13];
    float* out = (float*)d_out;
    int N = in_sizes[3];
    int E = in_sizes[2] / EDIM;
    float Ef = (float)E;
    int ntiles0 = (N + 63) / 64;

    float* ws = (float*)d_ws;
    size_t off = 0;
    unsigned short* h = (unsigned short*)(ws + off);
    float* hist_part = ws + off;                  // overlay: 13.1MB <= 25.6MB h region
    off += (size_t)N * HDIM / 2;                  // h as bf16
    float* partials = ws + off; off += (size_t)2048 * 512;
    float* mean_msg = ws + off; off += 128;
    float* c_src    = ws + off; off += CBINS;
    float* c_dst    = ws + off; off += CBINS;
    float* xpart    = ws + off; off += (size_t)NBX * 136;
    unsigned short* wtg = (unsigned short*)(ws + off); off += 128 * KP / 2;
    // ---- accumulator region (contiguous, zeroed every call) ----
    float* acc0     = ws + off;
    float* sum_attr = ws + off; off += 8;
    float* pooled   = ws + off; off += NGRAPHS * HDIM;
    size_t zero_count = (size_t)(ws + off - acc0);
    hipMemsetAsync(acc0, 0, zero_count * sizeof(float), stream);

    k_pre<<<2 * HR * HB + 64 + 1, 256, 0, stream>>>(ei, hist_part, E, ea,
                                                    sum_attr, w_node, wtg);
    k_hist_red<<<(CBINS + 255) / 256, 256, 0, stream>>>(hist_part, c_src, c_dst);
    k_xsum<<<NBX, 256, 0, stream>>>(x, c_src, c_dst, xpart, N);

    const int NB = 1024;
    int cpb = (N + NB - 1) / NB;

    // layer 0
    k_mm<1><<<8, 256, 0, stream>>>(xpart, NBX, sum_attr, w_edge, b_edge,
                                   mp_w, mp_b, mean_msg, Ef, w_node, b_node);
    k_upd0<<<ntiles0, 256, 0, stream>>>(x, wtg, b_node, mean_msg, ln_g, ln_b,
                                        c_src, c_dst, h, partials, N);
    // layer 1
    k_mm<0><<<8, 256, 0, stream>>>(partials, ntiles0, sum_attr, w_edge, b_edge,
                                   mp_w + (size_t)1 * 384 * HDIM,
                                   mp_b + (size_t)1 * HDIM, mean_msg, Ef,
                                   w_node, b_node);
    k_update<0><<<NB, 256, 0, stream>>>(h, mean_msg, ln_g, ln_b, c_src, c_dst,
                                        batch, partials, pooled, N, cpb);
    // layer 2
    k_mm<0><<<8, 256, 0, stream>>>(partials, NB, sum_attr, w_edge, b_edge,
                                   mp_w + (size_t)2 * 384 * HDIM,
                                   mp_b + (size_t)2 * HDIM, mean_msg, Ef,
                                   w_node, b_node);
    k_update<1><<<NB, 256, 0, stream>>>(h, mean_msg, ln_g, ln_b, c_src, c_dst,
                                        batch, partials, pooled, N, cpb);

    k_out<<<NGRAPHS, HDIM, 0, stream>>>(pooled, batch, w_out, b_out, out, N);
}

// Round 10
// 163.856 us; speedup vs baseline: 3.2284x; 3.2284x over previous
//
#include <hip/hip_runtime.h>

#define HDIM 128
#define XDIM 66
#define EDIM 6
#define NGRAPHS 256
#define LN_EPS 1e-5f

#define HBINS 25600          // bins per range (100 KB LDS)
#define HR 4                 // ranges: HR*HBINS = 102400 >= N
#define HB 16                // edge slices per (range, array)
#define CBINS (HR * HBINS)
#define NBX 1024             // k_xsum grid
#define KP 104               // padded K for bf16 MFMA

typedef __attribute__((ext_vector_type(8))) short sv8;
typedef __attribute__((ext_vector_type(4))) float fv4;

__device__ __forceinline__ unsigned short f2bf(float f) {
    unsigned u = __float_as_uint(f);
    return (unsigned short)((u + 0x7FFFu + ((u >> 16) & 1u)) >> 16);
}
__device__ __forceinline__ float bf2f(unsigned short u) {
    return __uint_as_float((unsigned)u << 16);
}

// ---------------- K1: hist partials + edge_attr colsum + W^T prep (merged) ----------------
__global__ __launch_bounds__(256) void k_pre(const int* __restrict__ ei,
        float* __restrict__ part, int E, const float* __restrict__ ea,
        float* __restrict__ sum_attr, const float* __restrict__ w_node,
        unsigned short* __restrict__ wtg) {
    __shared__ float lh[HBINS];
    int b = blockIdx.x;
    int t = threadIdx.x;
    if (b < 2 * HR * HB) {
        int s = b & (HB - 1);
        int r = (b / HB) & (HR - 1);
        int a = b / (HB * HR);
        for (int i = t; i < HBINS; i += 256) lh[i] = 0.f;
        __syncthreads();
        const int* src = ei + (size_t)a * E;
        int chunk = (((E + HB - 1) / HB) + 3) & ~3;
        int lo = s * chunk;
        int hi = min(E, lo + chunk);
        int base = r * HBINS;
        if ((E & 3) == 0) {
            for (int i = lo + t * 4; i < hi; i += 256 * 4) {
                if (i + 4 <= hi) {
                    int4 v = *(const int4*)(src + i);
                    unsigned u0 = (unsigned)(v.x - base);
                    unsigned u1 = (unsigned)(v.y - base);
                    unsigned u2 = (unsigned)(v.z - base);
                    unsigned u3 = (unsigned)(v.w - base);
                    if (u0 < HBINS) atomicAdd(&lh[u0], 1.0f);
                    if (u1 < HBINS) atomicAdd(&lh[u1], 1.0f);
                    if (u2 < HBINS) atomicAdd(&lh[u2], 1.0f);
                    if (u3 < HBINS) atomicAdd(&lh[u3], 1.0f);
                } else {
                    for (int j = i; j < hi; ++j) {
                        unsigned u = (unsigned)(src[j] - base);
                        if (u < HBINS) atomicAdd(&lh[u], 1.0f);
                    }
                }
            }
        } else {
            for (int i = lo + t; i < hi; i += 256) {
                unsigned u = (unsigned)(src[i] - base);
                if (u < HBINS) atomicAdd(&lh[u], 1.0f);
            }
        }
        __syncthreads();
        float* dst = part + (size_t)b * HBINS;
        for (int i = t; i < HBINS / 4; i += 256)
            ((float4*)dst)[i] = ((const float4*)lh)[i];
    } else if (b < 2 * HR * HB + 64) {
        int b2 = b - 2 * HR * HB;
        int nchunk = E >> 1;
        float a0 = 0, a1 = 0, a2 = 0, a3 = 0, a4 = 0, a5 = 0;
        for (int c = b2 * 256 + t; c < nchunk; c += 64 * 256) {
            const float4* p = (const float4*)(ea + (size_t)c * 12);
            float4 v0 = p[0], v1 = p[1], v2 = p[2];
            a0 += v0.x + v1.z;  a1 += v0.y + v1.w;  a2 += v0.z + v2.x;
            a3 += v0.w + v2.y;  a4 += v1.x + v2.z;  a5 += v1.y + v2.w;
        }
#pragma unroll
        for (int m = 32; m; m >>= 1) {
            a0 += __shfl_xor(a0, m); a1 += __shfl_xor(a1, m); a2 += __shfl_xor(a2, m);
            a3 += __shfl_xor(a3, m); a4 += __shfl_xor(a4, m); a5 += __shfl_xor(a5, m);
        }
        float (*sb)[6] = (float(*)[6])lh;
        int lane = t & 63, w = t >> 6;
        if (lane == 0) {
            sb[w][0] = a0; sb[w][1] = a1; sb[w][2] = a2;
            sb[w][3] = a3; sb[w][4] = a4; sb[w][5] = a5;
        }
        __syncthreads();
        if (t < 6) {
            float s = sb[0][t] + sb[1][t] + sb[2][t] + sb[3][t];
            atomicAdd(&sum_attr[t], s);
        }
        if (b2 == 0 && t < 6 && (E & 1))
            atomicAdd(&sum_attr[t], ea[(size_t)(E - 1) * 6 + t]);
    } else {
        if (t < 128) {
            for (int kp = 0; kp < KP; ++kp) {
                float v = (kp < XDIM) ? w_node[kp * HDIM + t] : 0.f;
                wtg[t * KP + kp] = f2bf(v);
            }
        }
    }
}

// ---------------- K1b: reduce slices -> c_src, c_dst ----------------
__global__ __launch_bounds__(256) void k_hist_red(const float* __restrict__ part,
        float* __restrict__ c_src, float* __restrict__ c_dst) {
    int n = blockIdx.x * 256 + threadIdx.x;
    if (n >= CBINS) return;
    int r = n / HBINS, off = n - r * HBINS;
    const float* p0 = part + ((size_t)(0 * HR + r) * HB) * HBINS + off;
    const float* p1 = part + ((size_t)(1 * HR + r) * HB) * HBINS + off;
    float s0 = 0.f, s1 = 0.f;
#pragma unroll 8
    for (int s = 0; s < HB; ++s) {
        s0 += p0[(size_t)s * HBINS];
        s1 += p1[(size_t)s * HBINS];
    }
    c_src[n] = s0;
    c_dst[n] = s1;
}

// ---------------- K3: weighted column sums of x -> per-block partials ----------------
__global__ __launch_bounds__(256) void k_xsum(const float* __restrict__ x,
        const float* __restrict__ c_src, const float* __restrict__ c_dst,
        float* __restrict__ xpart, int N) {
    int lane = threadIdx.x & 63, w = threadIdx.x >> 6;
    int wid = blockIdx.x * 4 + w, nw = gridDim.x * 4;
    float as0 = 0, ad0 = 0, as1 = 0, ad1 = 0;
    int Q = N >> 2;
    for (int q = wid; q < Q; q += nw) {
        int n = q * 4;
        const float* xr = x + (size_t)n * XDIM;
        float x0 = xr[lane];
        float x1 = xr[XDIM + lane];
        float x2 = xr[2 * XDIM + lane];
        float x3 = xr[3 * XDIM + lane];
        float4 cs = *(const float4*)(c_src + n);
        float4 cd = *(const float4*)(c_dst + n);
        as0 = fmaf(cs.x, x0, as0); as0 = fmaf(cs.y, x1, as0);
        as0 = fmaf(cs.z, x2, as0); as0 = fmaf(cs.w, x3, as0);
        ad0 = fmaf(cd.x, x0, ad0); ad0 = fmaf(cd.y, x1, ad0);
        ad0 = fmaf(cd.z, x2, ad0); ad0 = fmaf(cd.w, x3, ad0);
        if (lane < 2) {
            float e0 = xr[64 + lane];
            float e1 = xr[XDIM + 64 + lane];
            float e2 = xr[2 * XDIM + 64 + lane];
            float e3 = xr[3 * XDIM + 64 + lane];
            as1 = fmaf(cs.x, e0, as1); as1 = fmaf(cs.y, e1, as1);
            as1 = fmaf(cs.z, e2, as1); as1 = fmaf(cs.w, e3, as1);
            ad1 = fmaf(cd.x, e0, ad1); ad1 = fmaf(cd.y, e1, ad1);
            ad1 = fmaf(cd.z, e2, ad1); ad1 = fmaf(cd.w, e3, ad1);
        }
    }
    if (wid == 0) {
        for (int n = Q * 4; n < N; ++n) {
            const float* xr = x + (size_t)n * XDIM;
            float cs = c_src[n], cd = c_dst[n];
            float xv = xr[lane];
            as0 = fmaf(cs, xv, as0);
            ad0 = fmaf(cd, xv, ad0);
            if (lane < 2) {
                float xe = xr[64 + lane];
                as1 = fmaf(cs, xe, as1);
                ad1 = fmaf(cd, xe, ad1);
            }
        }
    }
    __shared__ float redS[4][XDIM], redD[4][XDIM];
    redS[w][lane] = as0;  redD[w][lane] = ad0;
    if (lane < 2) { redS[w][64 + lane] = as1;  redD[w][64 + lane] = ad1; }
    __syncthreads();
    int t = threadIdx.x;
    float* xp = xpart + (size_t)blockIdx.x * 136;
    if (t < XDIM) {
        xp[t]        = redS[0][t] + redS[1][t] + redS[2][t] + redS[3][t];
        xp[XDIM + t] = redD[0][t] + redD[1][t] + redD[2][t] + redD[3][t];
    }
}

// ---------------- K3b: reduce xpart rows -> xs[132] ----------------
__global__ __launch_bounds__(64) void k_xred(const float* __restrict__ xpart,
                                             float* __restrict__ xs, int nb) {
    int e = blockIdx.x;
    int lane = threadIdx.x;
    float s = 0.f;
    for (int b = lane; b < nb; b += 64)
        s += xpart[(size_t)b * 136 + e];
#pragma unroll
    for (int m = 32; m; m >>= 1) s += __shfl_xor(s, m);
    if (lane == 0) xs[e] = s;
}

// ---------------- K5: reduce per-block partials -> sbuf[512] (wide grid) ----------------
__global__ __launch_bounds__(256) void k_red(const float* __restrict__ partials,
                                             float* __restrict__ sbuf, int nb) {
    int b0 = blockIdx.x * 32;
    int b1 = min(nb, b0 + 32);
    int t = threadIdx.x;
    float s0 = 0.f, s1 = 0.f;
    for (int b = b0; b < b1; ++b) {
        const float* row = partials + (size_t)b * 512;
        s0 += row[t];
        s1 += row[t + 256];
    }
    atomicAdd(&sbuf[t], s0);
    atomicAdd(&sbuf[t + 256], s1);
}

// ---------------- K6: mean_msg = ([s_src,s_dst,se] @ W)/E + mp_b ----------------
// FIRST=1: sv = xs[136]; FIRST=0: sv = sbuf[512]
template <int FIRST>
__global__ __launch_bounds__(256) void k_mm(const float* __restrict__ sv,
        const float* __restrict__ sum_attr, const float* __restrict__ w_edge,
        const float* __restrict__ b_edge, const float* __restrict__ W,
        const float* __restrict__ mpb, float* __restrict__ mean_msg, float Ef,
        const float* __restrict__ w_node, const float* __restrict__ b_node) {
    __shared__ float sc[384];
    __shared__ float mred[256];
    int t = threadIdx.x;
    if (t < 128) {
        float ssrc, sdst;
        if (FIRST) {
            ssrc = Ef * b_node[t];
            sdst = ssrc;
#pragma unroll
            for (int k = 0; k < XDIM; ++k) {
                float wv = w_node[k * HDIM + t];
                ssrc = fmaf(sv[k], wv, ssrc);
                sdst = fmaf(sv[XDIM + k], wv, sdst);
            }
        } else {
            ssrc = sv[t] + sv[t + 128];
            sdst = sv[256 + t] + sv[384 + t];
        }
        sc[t] = ssrc;
        sc[128 + t] = sdst;
        float se = Ef * b_edge[t];
#pragma unroll
        for (int k = 0; k < EDIM; ++k) se = fmaf(sum_attr[k], w_edge[k * HDIM + t], se);
        sc[256 + t] = se;
    }
    __syncthreads();
    int col = blockIdx.x * 16 + (t & 15);
    int rg = t >> 4;
    float acc = 0.f;
#pragma unroll 4
    for (int r = rg * 24; r < rg * 24 + 24; ++r)
        acc = fmaf(sc[r], W[r * HDIM + col], acc);
    mred[t] = acc;
    __syncthreads();
    if (t < 16) {
        float s = 0.f;
#pragma unroll
        for (int g = 0; g < 16; ++g) s += mred[g * 16 + t];
        mean_msg[blockIdx.x * 16 + t] = s / Ef + mpb[blockIdx.x * 16 + t];
    }
}

// ---------------- K7: fused layer-0 via bf16 MFMA; h stored bf16 ----------------
__global__ __launch_bounds__(256) void k_upd0(
        const float* __restrict__ x, const unsigned short* __restrict__ wtg,
        const float* __restrict__ b_node, const float* __restrict__ mean_msg,
        const float* __restrict__ ln_g, const float* __restrict__ ln_b,
        const float* __restrict__ c_src, const float* __restrict__ c_dst,
        unsigned short* __restrict__ h, float* __restrict__ partials, int N) {
    __shared__ unsigned short xl[64 * KP];
    __shared__ unsigned short wt[128 * KP];
    int t = threadIdx.x;
    int lane = t & 63, w = t >> 6;
    {
        const uint4* srcp = (const uint4*)wtg;
        uint4* dstp = (uint4*)wt;
        for (int i = t; i < 128 * KP / 8; i += 256) dstp[i] = srcp[i];
    }
    for (int i = t; i < 64 * KP / 2; i += 256) ((unsigned*)xl)[i] = 0u;
    __syncthreads();
    int rowbase = blockIdx.x * 64;
    const float* xg = x + (size_t)rowbase * XDIM;
    int lim = min(64, N - rowbase) * XDIM;
    for (int i = t; i < 64 * XDIM; i += 256) {
        if (i < lim) {
            int r = i / XDIM, k = i - r * XDIM;
            xl[r * KP + k] = f2bf(xg[i]);
        }
    }
    int cl = lane & 15, g = lane >> 4;
    float bm[8], gg[8], lb[8];
#pragma unroll
    for (int ct = 0; ct < 8; ++ct) {
        int col = ct * 16 + cl;
        bm[ct] = b_node[col] + mean_msg[col];
        gg[ct] = ln_g[col];
        lb[ct] = ln_b[col];
    }
    __syncthreads();

    fv4 acc[8];
#pragma unroll
    for (int ct = 0; ct < 8; ++ct) acc[ct] = (fv4){0.f, 0.f, 0.f, 0.f};
#pragma unroll
    for (int ks = 0; ks < 3; ++ks) {
        sv8 a = *(const sv8*)&xl[(w * 16 + cl) * KP + ks * 32 + g * 8];
#pragma unroll
        for (int ct = 0; ct < 8; ++ct) {
            sv8 b = *(const sv8*)&wt[(ct * 16 + cl) * KP + ks * 32 + g * 8];
            acc[ct] = __builtin_amdgcn_mfma_f32_16x16x32_bf16(a, b, acc[ct], 0, 0, 0);
        }
    }
    float v[8][4];
    float s[4] = {0.f, 0.f, 0.f, 0.f};
#pragma unroll
    for (int ct = 0; ct < 8; ++ct)
#pragma unroll
        for (int e = 0; e < 4; ++e) {
            v[ct][e] = acc[ct][e] + bm[ct];
            s[e] += v[ct][e];
        }
#pragma unroll
    for (int m = 1; m < 16; m <<= 1) {
        s[0] += __shfl_xor(s[0], m); s[1] += __shfl_xor(s[1], m);
        s[2] += __shfl_xor(s[2], m); s[3] += __shfl_xor(s[3], m);
    }
    float mu[4], q[4] = {0.f, 0.f, 0.f, 0.f};
#pragma unroll
    for (int e = 0; e < 4; ++e) mu[e] = s[e] * (1.0f / HDIM);
#pragma unroll
    for (int ct = 0; ct < 8; ++ct)
#pragma unroll
        for (int e = 0; e < 4; ++e) {
            float d = v[ct][e] - mu[e];
            q[e] = fmaf(d, d, q[e]);
        }
#pragma unroll
    for (int m = 1; m < 16; m <<= 1) {
        q[0] += __shfl_xor(q[0], m); q[1] += __shfl_xor(q[1], m);
        q[2] += __shfl_xor(q[2], m); q[3] += __shfl_xor(q[3], m);
    }
    float rs[4];
#pragma unroll
    for (int e = 0; e < 4; ++e) rs[e] = rsqrtf(q[e] * (1.0f / HDIM) + LN_EPS);

    int grow = rowbase + w * 16 + g * 4;
    float4 csv = *(const float4*)(c_src + grow);
    float4 cdv = *(const float4*)(c_dst + grow);
    float cs[4] = {csv.x, csv.y, csv.z, csv.w};
    float cd[4] = {cdv.x, cdv.y, cdv.z, cdv.w};
    float accS[8], accD[8];
#pragma unroll
    for (int ct = 0; ct < 8; ++ct) { accS[ct] = 0.f; accD[ct] = 0.f; }
#pragma unroll
    for (int e = 0; e < 4; ++e) {
        int row = grow + e;
        bool ok = (row < N);
#pragma unroll
        for (int ct = 0; ct < 8; ++ct) {
            float o = fmaxf(0.f, fmaf((v[ct][e] - mu[e]) * rs[e], gg[ct], lb[ct]));
            if (ok) h[(size_t)row * HDIM + ct * 16 + cl] = f2bf(o);
            accS[ct] = fmaf(cs[e], o, accS[ct]);
            accD[ct] = fmaf(cd[e], o, accD[ct]);
        }
    }
#pragma unroll
    for (int ct = 0; ct < 8; ++ct) {
        accS[ct] += __shfl_xor(accS[ct], 16); accS[ct] += __shfl_xor(accS[ct], 32);
        accD[ct] += __shfl_xor(accD[ct], 16); accD[ct] += __shfl_xor(accD[ct], 32);
    }
    __syncthreads();
    float* redS = (float*)xl;
    float* redD = redS + 512;
    if (g == 0) {
#pragma unroll
        for (int ct = 0; ct < 8; ++ct) {
            redS[w * HDIM + ct * 16 + cl] = accS[ct];
            redD[w * HDIM + ct * 16 + cl] = accD[ct];
        }
    }
    __syncthreads();
    if (t < 128) {
        float ss = redS[t] + redS[128 + t] + redS[256 + t] + redS[384 + t];
        float dd = redD[t] + redD[128 + t] + redD[256 + t] + redD[384 + t];
        float* row = partials + (size_t)blockIdx.x * 512;
        row[t] = ss;       row[t + 128] = 0.f;
        row[t + 256] = dd; row[t + 384] = 0.f;
    }
}

// ---------------- LN helper: 32-lane group, 4 cols/lane ----------------
__device__ __forceinline__ float4 ln_row4(const unsigned short* hp,
        float4 mm, float4 g, float4 bb) {
    ushort4 hv = *(const ushort4*)hp;
    float4 v;
    v.x = bf2f(hv.x) + mm.x; v.y = bf2f(hv.y) + mm.y;
    v.z = bf2f(hv.z) + mm.z; v.w = bf2f(hv.w) + mm.w;
    float s = v.x + v.y + v.z + v.w;
#pragma unroll
    for (int m = 1; m < 32; m <<= 1) s += __shfl_xor(s, m);
    float mu = s * (1.0f / HDIM);
    float d0 = v.x - mu, d1 = v.y - mu, d2 = v.z - mu, d3 = v.w - mu;
    float q = d0 * d0 + d1 * d1 + d2 * d2 + d3 * d3;
#pragma unroll
    for (int m = 1; m < 32; m <<= 1) q += __shfl_xor(q, m);
    float rs = rsqrtf(q * (1.0f / HDIM) + LN_EPS);
    float4 o;
    o.x = fmaxf(0.f, fmaf(d0 * rs, g.x, bb.x));
    o.y = fmaxf(0.f, fmaf(d1 * rs, g.y, bb.y));
    o.z = fmaxf(0.f, fmaf(d2 * rs, g.z, bb.z));
    o.w = fmaxf(0.f, fmaf(d3 * rs, g.w, bb.w));
    return o;
}

// ---------------- K8: h = relu(LN(h + mm)) bf16; next-layer sums or pooling ----------------
template <int LAST>
__global__ __launch_bounds__(256) void k_update(
        unsigned short* __restrict__ h, const float* __restrict__ mean_msg,
        const float* __restrict__ ln_g, const float* __restrict__ ln_b,
        const float* __restrict__ c_src, const float* __restrict__ c_dst,
        const int* __restrict__ batch, float* __restrict__ partials,
        float* __restrict__ pooled, int N, int cpb) {
    int t = threadIdx.x;
    int lane = t & 63, w = t >> 6;
    int half = lane >> 5, cl = lane & 31;
    int c0 = cl * 4;
    float4 mm = *(const float4*)(mean_msg + c0);
    float4 g  = *(const float4*)(ln_g + c0);
    float4 bb = *(const float4*)(ln_b + c0);
    int start = blockIdx.x * cpb;
    int end = min(N, start + cpb);
    int spw = (cpb + 3) >> 2;
    int ns = start + w * spw;
    int ne = min(end, ns + spw);
    float4 accS = {0,0,0,0}, accD = {0,0,0,0}, accP = {0,0,0,0};
    int cur_g = -1;
    int n = ns;
    for (; n + 4 <= ne; n += 4) {
        int rA = n + half, rB = n + 2 + half;
        float4 oA = ln_row4(h + (size_t)rA * HDIM + c0, mm, g, bb);
        float4 oB = ln_row4(h + (size_t)rB * HDIM + c0, mm, g, bb);
        if (LAST) {
            int gA = batch[rA], gB = batch[rB];
            if (gA != cur_g) {
                if (cur_g >= 0) {
                    atomicAdd(&pooled[cur_g * HDIM + c0],     accP.x);
                    atomicAdd(&pooled[cur_g * HDIM + c0 + 1], accP.y);
                    atomicAdd(&pooled[cur_g * HDIM + c0 + 2], accP.z);
                    atomicAdd(&pooled[cur_g * HDIM + c0 + 3], accP.w);
                }
                accP = (float4){0,0,0,0};
                cur_g = gA;
            }
            accP.x += oA.x; accP.y += oA.y; accP.z += oA.z; accP.w += oA.w;
            if (gB != cur_g) {
                if (cur_g >= 0) {
                    atomicAdd(&pooled[cur_g * HDIM + c0],     accP.x);
                    atomicAdd(&pooled[cur_g * HDIM + c0 + 1], accP.y);
                    atomicAdd(&pooled[cur_g * HDIM + c0 + 2], accP.z);
                    atomicAdd(&pooled[cur_g * HDIM + c0 + 3], accP.w);
                }
                accP = (float4){0,0,0,0};
                cur_g = gB;
            }
            accP.x += oB.x; accP.y += oB.y; accP.z += oB.z; accP.w += oB.w;
        } else {
            ushort4 pA = {f2bf(oA.x), f2bf(oA.y), f2bf(oA.z), f2bf(oA.w)};
            ushort4 pB = {f2bf(oB.x), f2bf(oB.y), f2bf(oB.z), f2bf(oB.w)};
            *(ushort4*)(h + (size_t)rA * HDIM + c0) = pA;
            *(ushort4*)(h + (size_t)rB * HDIM + c0) = pB;
            float csA = c_src[rA], cdA = c_dst[rA];
            float csB = c_src[rB], cdB = c_dst[rB];
            accS.x = fmaf(csA, oA.x, accS.x); accS.y = fmaf(csA, oA.y, accS.y);
            accS.z = fmaf(csA, oA.z, accS.z); accS.w = fmaf(csA, oA.w, accS.w);
            accS.x = fmaf(csB, oB.x, accS.x); accS.y = fmaf(csB, oB.y, accS.y);
            accS.z = fmaf(csB, oB.z, accS.z); accS.w = fmaf(csB, oB.w, accS.w);
            accD.x = fmaf(cdA, oA.x, accD.x); accD.y = fmaf(cdA, oA.y, accD.y);
            accD.z = fmaf(cdA, oA.z, accD.z); accD.w = fmaf(cdA, oA.w, accD.w);
            accD.x = fmaf(cdB, oB.x, accD.x); accD.y = fmaf(cdB, oB.y, accD.y);
            accD.z = fmaf(cdB, oB.z, accD.z); accD.w = fmaf(cdB, oB.w, accD.w);
        }
    }
    for (; n < ne; n += 2) {
        int row = n + half;
        bool ok = row < ne;
        int rsafe = ok ? row : (N - 1);
        float4 o = ln_row4(h + (size_t)rsafe * HDIM + c0, mm, g, bb);
        if (LAST) {
            if (ok) {
                int gg2 = batch[row];
                if (gg2 != cur_g) {
                    if (cur_g >= 0) {
                        atomicAdd(&pooled[cur_g * HDIM + c0],     accP.x);
                        atomicAdd(&pooled[cur_g * HDIM + c0 + 1], accP.y);
                        atomicAdd(&pooled[cur_g * HDIM + c0 + 2], accP.z);
                        atomicAdd(&pooled[cur_g * HDIM + c0 + 3], accP.w);
                    }
                    accP = (float4){0,0,0,0};
                    cur_g = gg2;
                }
                accP.x += o.x; accP.y += o.y; accP.z += o.z; accP.w += o.w;
            }
        } else if (ok) {
            ushort4 pk = {f2bf(o.x), f2bf(o.y), f2bf(o.z), f2bf(o.w)};
            *(ushort4*)(h + (size_t)row * HDIM + c0) = pk;
            float cs = c_src[row], cd = c_dst[row];
            accS.x = fmaf(cs, o.x, accS.x); accS.y = fmaf(cs, o.y, accS.y);
            accS.z = fmaf(cs, o.z, accS.z); accS.w = fmaf(cs, o.w, accS.w);
            accD.x = fmaf(cd, o.x, accD.x); accD.y = fmaf(cd, o.y, accD.y);
            accD.z = fmaf(cd, o.z, accD.z); accD.w = fmaf(cd, o.w, accD.w);
        }
    }
    if (LAST) {
        if (cur_g >= 0) {
            atomicAdd(&pooled[cur_g * HDIM + c0],     accP.x);
            atomicAdd(&pooled[cur_g * HDIM + c0 + 1], accP.y);
            atomicAdd(&pooled[cur_g * HDIM + c0 + 2], accP.z);
            atomicAdd(&pooled[cur_g * HDIM + c0 + 3], accP.w);
        }
    } else {
        __shared__ float redS[8][HDIM], redD[8][HDIM];
        int set = (w << 1) | half;
        *(float4*)(&redS[set][c0]) = accS;
        *(float4*)(&redD[set][c0]) = accD;
        __syncthreads();
        if (t < 128) {
            float ss = 0.f, dd = 0.f;
#pragma unroll
            for (int gi = 0; gi < 8; ++gi) {
                ss += redS[gi][t];
                dd += redD[gi][t];
            }
            float* row = partials + (size_t)blockIdx.x * 512;
            row[t] = ss;       row[t + 128] = 0.f;
            row[t + 256] = dd; row[t + 384] = 0.f;
        }
    }
}

// ---------------- K9: out = (pooled / max(cnt,1)) @ w_out + b_out ----------------
__global__ __launch_bounds__(128) void k_out(const float* __restrict__ pooled,
        const int* __restrict__ batch, const float* __restrict__ w_out,
        const float* __restrict__ b_out, float* __restrict__ out, int N) {
    int gph = blockIdx.x;
    int t = threadIdx.x;
    __shared__ float p[HDIM];
    __shared__ int cntS;
    if (t == 0) {
        int lo = 0, hi = N;
        while (lo < hi) { int mid = (lo + hi) >> 1; if (batch[mid] < gph) lo = mid + 1; else hi = mid; }
        int lo2 = lo, hi2 = N;
        while (lo2 < hi2) { int mid = (lo2 + hi2) >> 1; if (batch[mid] <= gph) lo2 = mid + 1; else hi2 = mid; }
        cntS = lo2 - lo;
    }
    __syncthreads();
    float inv = 1.0f / fmaxf((float)cntS, 1.0f);
    p[t] = pooled[gph * HDIM + t] * inv;
    __syncthreads();
    float acc = b_out[t];
#pragma unroll 8
    for (int k = 0; k < HDIM; ++k) acc = fmaf(p[k], w_out[k * HDIM + t], acc);
    out[gph * HDIM + t] = acc;
}

extern "C" void kernel_launch(void* const* d_in, const int* in_sizes, int n_in,
                              void* d_out, int out_size, void* d_ws, size_t ws_size,
                              hipStream_t stream) {
    const float* x      = (const float*)d_in[0];
    const int*   ei     = (const int*)d_in[1];
    const float* ea     = (const float*)d_in[2];
    const int*   batch  = (const int*)d_in[3];
    const float* w_node = (const float*)d_in[4];
    const float* b_node = (const float*)d_in[5];
    const float* w_edge = (const float*)d_in[6];
    const float* b_edge = (const float*)d_in[7];
    const float* mp_w   = (const float*)d_in[8];
    const float* mp_b   = (const float*)d_in[9];
    const float* ln_g   = (const float*)d_in[10];
    const float* ln_b   = (const float*)d_in[11];
    const float* w_out  = (const float*)d_in[12];
    const float* b_out  = (const float*)d_in[13];
    float* out = (float*)d_out;
    int N = in_sizes[3];
    int E = in_sizes[2] / EDIM;
    float Ef = (float)E;
    int ntiles0 = (N + 63) / 64;

    float* ws = (float*)d_ws;
    size_t off = 0;
    unsigned short* h = (unsigned short*)(ws + off);
    float* hist_part = ws + off;                  // overlay: 13.1MB <= 25.6MB h region
    off += (size_t)N * HDIM / 2;                  // h as bf16
    float* partials = ws + off; off += (size_t)2048 * 512;
    float* mean_msg = ws + off; off += 128;
    float* c_src    = ws + off; off += CBINS;
    float* c_dst    = ws + off; off += CBINS;
    float* xpart    = ws + off; off += (size_t)NBX * 136;
    unsigned short* wtg = (unsigned short*)(ws + off); off += 128 * KP / 2;
    float* xs       = ws + off; off += 136;       // fully written by k_xred
    // ---- accumulator region (contiguous, zeroed every call) ----
    float* acc0     = ws + off;
    float* sum_attr = ws + off; off += 8;
    float* sbuf1    = ws + off; off += 512;
    float* sbuf2    = ws + off; off += 512;
    float* pooled   = ws + off; off += NGRAPHS * HDIM;
    size_t zero_count = (size_t)(ws + off - acc0);
    hipMemsetAsync(acc0, 0, zero_count * sizeof(float), stream);

    k_pre<<<2 * HR * HB + 64 + 1, 256, 0, stream>>>(ei, hist_part, E, ea,
                                                    sum_attr, w_node, wtg);
    k_hist_red<<<(CBINS + 255) / 256, 256, 0, stream>>>(hist_part, c_src, c_dst);
    k_xsum<<<NBX, 256, 0, stream>>>(x, c_src, c_dst, xpart, N);
    k_xred<<<2 * XDIM, 64, 0, stream>>>(xpart, xs, NBX);

    const int NB = 1024;
    int cpb = (N + NB - 1) / NB;

    // layer 0
    k_mm<1><<<8, 256, 0, stream>>>(xs, sum_attr, w_edge, b_edge,
                                   mp_w, mp_b, mean_msg, Ef, w_node, b_node);
    k_upd0<<<ntiles0, 256, 0, stream>>>(x, wtg, b_node, mean_msg, ln_g, ln_b,
                                        c_src, c_dst, h, partials, N);
    // layer 1
    k_red<<<(ntiles0 + 31) / 32, 256, 0, stream>>>(partials, sbuf1, ntiles0);
    k_mm<0><<<8, 256, 0, stream>>>(sbuf1, sum_attr, w_edge, b_edge,
                                   mp_w + (size_t)1 * 384 * HDIM,
                                   mp_b + (size_t)1 * HDIM, mean_msg, Ef,
                                   w_node, b_node);
    k_update<0><<<NB, 256, 0, stream>>>(h, mean_msg, ln_g, ln_b, c_src, c_dst,
                                        batch, partials, pooled, N, cpb);
    // layer 2
    k_red<<<NB / 32, 256, 0, stream>>>(partials, sbuf2, NB);
    k_mm<0><<<8, 256, 0, stream>>>(sbuf2, sum_attr, w_edge, b_edge,
                                   mp_w + (size_t)2 * 384 * HDIM,
                                   mp_b + (size_t)2 * HDIM, mean_msg, Ef,
                                   w_node, b_node);
    k_update<1><<<NB, 256, 0, stream>>>(h, mean_msg, ln_g, ln_b, c_src, c_dst,
                                        batch, partials, pooled, N, cpb);

    k_out<<<NGRAPHS, HDIM, 0, stream>>>(pooled, batch, w_out, b_out, out, N);
}